// Round 4
// baseline (279.704 us; speedup 1.0000x reference)
//
#include <hip/hip_runtime.h>
#include <stdint.h>

// Problem constants: B=1, N=4096, C=256, H=8, D=64, H*D=512
#define NN 4096
#define CC 256
#define HD 512
#define DD 64
#define KSPLIT 4               // 64 k-tiles split 16/16/16/16 -> grid 2048 = 8 blocks/CU

typedef __attribute__((ext_vector_type(8))) short short8;
typedef __attribute__((ext_vector_type(4))) float floatx4;

__device__ __forceinline__ unsigned short f2bf(float x) {
    union { float f; unsigned int u; } v; v.f = x;
    unsigned int u = v.u + 0x7fffu + ((v.u >> 16) & 1u);
    return (unsigned short)(u >> 16);
}
__device__ __forceinline__ float bf2f(unsigned short s) {
    union { unsigned int u; float f; } v; v.u = ((unsigned int)s) << 16;
    return v.f;
}

// Pack two f32 -> bf16x2 (lo = first arg), RNE. HW instr on gfx950.
#if defined(__has_builtin) && __has_builtin(__builtin_amdgcn_cvt_pk_bf16_f32)
typedef __attribute__((ext_vector_type(2))) __bf16 bf16x2_t;
__device__ __forceinline__ unsigned int pack2bf(float a, float b) {
    union { bf16x2_t v; unsigned int u; } x;
    x.v = __builtin_amdgcn_cvt_pk_bf16_f32(a, b);
    return x.u;
}
#else
__device__ __forceinline__ unsigned int pack2bf(float a, float b) {
    return ((unsigned int)f2bf(b) << 16) | (unsigned int)f2bf(a);
}
#endif

// Async global->LDS, 16 B per lane; LDS dest = wave-uniform base + lane*16.
#define GLOAD_LDS(gp, lp) __builtin_amdgcn_global_load_lds(                    \
    (__attribute__((address_space(1))) void*)(gp),                             \
    (__attribute__((address_space(3))) void*)(lp), 16, 0, 0)

// ---------------------------------------------------------------------------
// Kernel 0: fp32 -> bf16 prep. z selects region. wq pre-scaled by 0.125.
// ---------------------------------------------------------------------------
__global__ __launch_bounds__(256) void prep_kernel(
    const float* __restrict__ qx, const float* __restrict__ kx,
    const float* __restrict__ vx,
    const float* __restrict__ wq, const float* __restrict__ wk,
    const float* __restrict__ wv, const float* __restrict__ wg,
    const float* __restrict__ wo,
    unsigned short* __restrict__ qxb, unsigned short* __restrict__ kxb,
    unsigned short* __restrict__ vxb, unsigned short* __restrict__ Wb,
    unsigned short* __restrict__ wob)
{
    const int z = blockIdx.y;
    const float* src; unsigned short* dst; int n; float s = 1.0f;
    switch (z) {
        case 0: src = qx; dst = qxb; n = NN * CC; break;
        case 1: src = kx; dst = kxb; n = NN * CC; break;
        case 2: src = vx; dst = vxb; n = NN * CC; break;
        case 3: src = wq; dst = Wb;               n = HD * CC; s = 0.125f; break;
        case 4: src = wk; dst = Wb + 1 * HD * CC; n = HD * CC; break;
        case 5: src = wv; dst = Wb + 2 * HD * CC; n = HD * CC; break;
        case 6: src = wg; dst = Wb + 3 * HD * CC; n = HD * CC; break;
        default: src = wo; dst = wob;             n = CC * HD; break;
    }
    int i = (blockIdx.x * 256 + threadIdx.x) * 4;
    if (i < n) {
        float4 v = *(const float4*)&src[i];
        ushort4 p;
        p.x = f2bf(v.x * s); p.y = f2bf(v.y * s);
        p.z = f2bf(v.z * s); p.w = f2bf(v.w * s);
        *(ushort4*)&dst[i] = p;
    }
}

// ---------------------------------------------------------------------------
// Kernel 1: fused projection GEMM. X[4096][256]bf16 @ Wb[2048][256]^T.
// Tile 128x128, BK=64. Staging via global_load_lds (16B/lane) into UNPADDED
// rows (64 shorts = 128 B) with XOR chunk swizzle: LDS slot j of row r holds
// source 8-short chunk j^(r&7); reads XOR the same way -> conflict-free.
// ---------------------------------------------------------------------------
__global__ __launch_bounds__(256, 4) void proj_kernel(
    const unsigned short* __restrict__ qxb, const unsigned short* __restrict__ kxb,
    const unsigned short* __restrict__ vxb, const unsigned short* __restrict__ Wb,
    const float* __restrict__ bg,
    unsigned short* __restrict__ Qb, unsigned short* __restrict__ Kb,
    unsigned short* __restrict__ VbT, unsigned short* __restrict__ Gb)
{
    const int m0 = blockIdx.x * 128;
    const int nb = blockIdx.y;
    const int n0 = nb * 128;
    const int mode = nb >> 2;
    const unsigned short* X = (mode == 1) ? kxb : (mode == 2) ? vxb : qxb;

    const int tid = threadIdx.x;
    const int wid = tid >> 6;
    const int wr = wid >> 1, wc = wid & 1;
    const int lane = tid & 63;
    const int quad = lane >> 4;
    const int ln = lane & 15;
    const int lnx = ln & 7;

    // Xs: 128x64 @ smem[0], Ws: 128x64 @ smem[8192]; transpose scratch reuses
    // the whole buffer (128x136 = 17408 shorts) after the final barrier.
    __shared__ __align__(16) unsigned short smem[128 * 136];
    unsigned short* Xs = smem;
    unsigned short* Ws = smem + 128 * 64;

    floatx4 acc[4][4] = {};

    for (int k0 = 0; k0 < CC; k0 += 64) {
        #pragma unroll
        for (int t = 0; t < 4; t++) {
            int row = wid * 32 + t * 8 + (lane >> 3);
            int c = (lane & 7) ^ (lane >> 3);
            GLOAD_LDS(&X[(size_t)(m0 + row) * CC + k0 + c * 8],
                      &Xs[(wid * 32 + t * 8) * 64]);
            GLOAD_LDS(&Wb[(size_t)(n0 + row) * CC + k0 + c * 8],
                      &Ws[(wid * 32 + t * 8) * 64]);
        }
        __syncthreads();

        #pragma unroll
        for (int ks = 0; ks < 64; ks += 32) {
            const int cb = ks >> 3;    // 0 or 4
            short8 a[4], b[4];
            #pragma unroll
            for (int i = 0; i < 4; i++)
                a[i] = *(const short8*)&Xs[(wr * 64 + i * 16 + ln) * 64 +
                                           (((quad ^ cb) ^ lnx) * 8)];
            #pragma unroll
            for (int j = 0; j < 4; j++)
                b[j] = *(const short8*)&Ws[(wc * 64 + j * 16 + ln) * 64 +
                                           (((quad ^ cb) ^ lnx) * 8)];
            #pragma unroll
            for (int i = 0; i < 4; i++)
                #pragma unroll
                for (int j = 0; j < 4; j++)
                    acc[i][j] = __builtin_amdgcn_mfma_f32_16x16x32_bf16(a[i], b[j], acc[i][j], 0, 0, 0);
        }
        __syncthreads();
    }

    const int subn = nb & 3;
    if (mode != 2) {
        unsigned short* Out = (mode == 0) ? Qb : (mode == 1) ? Kb : Gb;
        #pragma unroll
        for (int i = 0; i < 4; i++) {
            #pragma unroll
            for (int j = 0; j < 4; j++) {
                int col = subn * 128 + wc * 64 + j * 16 + ln;
                float bgv = (mode == 3) ? bg[col] : 0.0f;
                #pragma unroll
                for (int r = 0; r < 4; r++) {
                    int row = m0 + wr * 64 + i * 16 + quad * 4 + r;
                    float v = acc[i][j][r];
                    if (mode == 3) v = 1.0f / (1.0f + __expf(-(v + bgv)));
                    Out[(size_t)row * HD + col] = f2bf(v);
                }
            }
        }
    } else {
        // V: transpose through smem, store coalesced to VbT[col][row]
        #pragma unroll
        for (int i = 0; i < 4; i++) {
            #pragma unroll
            for (int j = 0; j < 4; j++) {
                int cl = wc * 64 + j * 16 + ln;
                #pragma unroll
                for (int r = 0; r < 4; r++) {
                    int rl = wr * 64 + i * 16 + quad * 4 + r;
                    smem[cl * 136 + rl] = f2bf(acc[i][j][r]);
                }
            }
        }
        __syncthreads();
        #pragma unroll
        for (int it = 0; it < 8; it++) {
            int idx = it * 256 + tid;
            int c = idx >> 4, ch = idx & 15;
            short8 vv = *(const short8*)&smem[c * 136 + ch * 8];
            *(short8*)&VbT[(size_t)(subn * 128 + c) * NN + m0 + ch * 8] = vv;
        }
    }
}

// ---------------------------------------------------------------------------
// Kernel 2: flash attention — r0 body (proven 82.6 µs) with LDS shrunk to
// exactly 20 KB so 8 blocks/CU fit (was 25.6 KB -> 6/CU). Ps becomes a
// 64x32 half-tile reused across the two PV passes r0 already had:
//   exp(n0,n1) -> PV(ks=0) -> exp(n2,n3) -> PV(ks=32)   (wave-private Ps,
// no extra barriers; DS ops in-order within a wave). Ps slot XOR
// (chunk ^ ((row>>1)&3)) makes both the u16 writes and the b128 A-reads
// conflict-free at 8-lane service granularity.
// KSPLIT=4 -> grid 2048 = 8 blocks/CU exact. VGPR cap 64 (was 40 measured).
// ---------------------------------------------------------------------------
__global__ __launch_bounds__(256, 8) void attn_kernel(
    const unsigned short* __restrict__ Qb, const unsigned short* __restrict__ Kb,
    const unsigned short* __restrict__ VbT,
    const float* __restrict__ bias,
    unsigned short* __restrict__ Opart, float* __restrict__ Lpart)
{
    const int h = blockIdx.y;
    const int q0 = blockIdx.x * 64;
    const int sp = blockIdx.z;
    const int tbeg = sp * 16;
    const int tend = tbeg + 16;
    const int tid = threadIdx.x;
    const int wid = tid >> 6;
    const int lane = tid & 63;
    const int quad = lane >> 4;
    const int ln = lane & 15;
    const int lnx = ln & 7;
    const int sc = (lane & 7) ^ (lane >> 3);

    __shared__ __align__(16) unsigned short Ks[64 * 64];   // 8 KB, swizzled
    __shared__ __align__(16) unsigned short Vs[64 * 64];   // 8 KB, swizzled [d][key]
    __shared__ __align__(16) unsigned short Ps[64 * 32];   // 4 KB half-tile, slot-XOR

    // Q A-fragments in registers for the whole kernel
    const int qrow = q0 + wid * 16 + ln;
    short8 qa0 = *(const short8*)&Qb[(size_t)qrow * HD + h * DD + quad * 8];
    short8 qa1 = *(const short8*)&Qb[(size_t)qrow * HD + h * DD + 32 + quad * 8];

    floatx4 O[4] = {};
    float lsum[4] = {0.0f, 0.0f, 0.0f, 0.0f};

    for (int kt = tbeg; kt < tend; kt++) {
        const int k0 = kt * 64;
        // async staging: 16 B/lane, LDS slot j of row r <- source chunk j^(r&7)
        #pragma unroll
        for (int t = 0; t < 2; t++) {
            int row = wid * 16 + t * 8 + (lane >> 3);
            GLOAD_LDS(&Kb[(size_t)(k0 + row) * HD + h * DD + sc * 8],
                      &Ks[(wid * 16 + t * 8) * 64]);
            GLOAD_LDS(&VbT[(size_t)(h * DD + row) * NN + k0 + sc * 8],
                      &Vs[(wid * 16 + t * 8) * 64]);
        }

        // bias -> registers (overlaps barrier drain); feeds MFMA C-init
        float bv[4][4];
        #pragma unroll
        for (int r = 0; r < 4; r++) {
            const float* brow = &bias[(size_t)(q0 + wid * 16 + quad * 4 + r) * NN + k0];
            #pragma unroll
            for (int n = 0; n < 4; n++) bv[r][n] = brow[n * 16 + ln];
        }
        __syncthreads();

        // S = Q K^T + bias (bias as accumulator init; C layout matches bv[r][n])
        floatx4 S[4];
        #pragma unroll
        for (int n = 0; n < 4; n++)
            S[n] = (floatx4){bv[0][n], bv[1][n], bv[2][n], bv[3][n]};
        #pragma unroll
        for (int n = 0; n < 4; n++) {
            short8 b0 = *(const short8*)&Ks[(n * 16 + ln) * 64 + ((quad ^ lnx) * 8)];
            S[n] = __builtin_amdgcn_mfma_f32_16x16x32_bf16(qa0, b0, S[n], 0, 0, 0);
            short8 b1 = *(const short8*)&Ks[(n * 16 + ln) * 64 + (((quad ^ 4) ^ lnx) * 8)];
            S[n] = __builtin_amdgcn_mfma_f32_16x16x32_bf16(qa1, b1, S[n], 0, 0, 0);
        }

        // two half-passes over the 64 keys; Ps half-tile reused (wave-private)
        #pragma unroll
        for (int half = 0; half < 2; half++) {
            const int nlo = half * 2;
            // p = exp(S); fixed-max softmax (logits bounded), packed bf16.
            // chunk c of row r stored at slot c ^ ((r>>1)&3).
            #pragma unroll
            for (int r = 0; r < 4; r++) {
                const int prow = wid * 16 + quad * 4 + r;
                const int rx = (prow >> 1) & 3;
                const int pb = prow * 32 + (ln & 7);
                float p0 = __expf(S[nlo][r]);
                float p1 = __expf(S[nlo + 1][r]);
                lsum[r] += p0 + p1;
                unsigned int pk = pack2bf(p0, p1);
                const int c0 = ln >> 3;
                Ps[pb + (((c0) ^ rx) * 8)]     = (unsigned short)(pk & 0xffffu);
                Ps[pb + (((2 + c0) ^ rx) * 8)] = (unsigned short)(pk >> 16);
            }
            // O += P V for this 32-key half
            const int ks = half * 32;
            const int cb = ks >> 3;
            const int arow = wid * 16 + ln;
            short8 a = *(const short8*)&Ps[arow * 32 +
                                           ((quad ^ ((arow >> 1) & 3)) * 8)];
            #pragma unroll
            for (int nd = 0; nd < 4; nd++) {
                short8 b = *(const short8*)&Vs[(nd * 16 + ln) * 64 +
                                               (((quad ^ cb) ^ lnx) * 8)];
                O[nd] = __builtin_amdgcn_mfma_f32_16x16x32_bf16(a, b, O[nd], 0, 0, 0);
            }
        }
        __syncthreads();
    }

    // epilogue: one 16-lane reduction for l; store O partial (bf16) + l
    #pragma unroll
    for (int r = 0; r < 4; r++) {
        #pragma unroll
        for (int off = 1; off < 16; off <<= 1)
            lsum[r] += __shfl_xor(lsum[r], off);
        int grow = q0 + wid * 16 + quad * 4 + r;
        size_t base = ((size_t)(sp * 8 + h) * NN + grow) * 64;
        #pragma unroll
        for (int nd = 0; nd < 4; nd++)
            Opart[base + nd * 16 + ln] = f2bf(O[nd][r]);
        if (ln == 0)
            Lpart[(size_t)(sp * 8 + h) * NN + grow] = lsum[r];
    }
}

// ---------------------------------------------------------------------------
// Kernel 3 (fused): combine split-K partials + normalize + gate computed in
// registers during X staging (ds_write into the same XOR layout), then
// out = OG @ wob^T + bo. Eliminates the combine kernel and the OGb buffer.
// ---------------------------------------------------------------------------
__global__ __launch_bounds__(256, 4) void outproj_kernel(
    const unsigned short* __restrict__ Opart, const float* __restrict__ Lpart,
    const unsigned short* __restrict__ Gb, const unsigned short* __restrict__ wob,
    const float* __restrict__ bo, float* __restrict__ out)
{
    const int m0 = blockIdx.x * 64;
    const int n0 = blockIdx.y * 64;
    const int tid = threadIdx.x;
    const int wid = tid >> 6;
    const int lane = tid & 63;
    const int quad = lane >> 4;
    const int ln = lane & 15;
    const int lnx = ln & 7;

    __shared__ __align__(16) unsigned short Xs[64 * 64];
    __shared__ __align__(16) unsigned short Ws[64 * 64];

    floatx4 acc[4] = {};

    for (int h = 0; h < 8; h++) {           // k0 = h*64: one head per K-step
        // Ws: wob panel via async DMA (XOR chunk layout)
        #pragma unroll
        for (int t = 0; t < 2; t++) {
            int row = wid * 16 + t * 8 + (lane >> 3);
            int c = (lane & 7) ^ (lane >> 3);
            GLOAD_LDS(&wob[(size_t)(n0 + row) * HD + h * 64 + c * 8],
                      &Ws[(wid * 16 + t * 8) * 64]);
        }
        // Xs: OG tile computed in registers (combine+gate), ds_write_b128
        // at slot lane&7 (holds chunk (lane&7)^(row&7) -> same XOR layout;
        // each 8-lane write group = 1 row x 8 slots -> conflict-free).
        #pragma unroll
        for (int t = 0; t < 2; t++) {
            int row = wid * 16 + t * 8 + (lane >> 3);
            int q = m0 + row;
            int c = (lane & 7) ^ (lane >> 3);
            int d0 = c * 8;
            float l = 0.0f;
            float ov[8] = {};
            #pragma unroll
            for (int sp = 0; sp < KSPLIT; sp++) {
                size_t idx = (size_t)(sp * 8 + h) * NN + q;
                l += Lpart[idx];
                short8 o8 = *(const short8*)&Opart[idx * 64 + d0];
                #pragma unroll
                for (int j = 0; j < 8; j++) ov[j] += bf2f((unsigned short)o8[j]);
            }
            float inv = 1.0f / l;
            short8 g8 = *(const short8*)&Gb[(size_t)q * HD + h * 64 + d0];
            union { unsigned int u[4]; short8 s; } pk;
            #pragma unroll
            for (int j = 0; j < 4; j++)
                pk.u[j] = pack2bf(ov[2 * j] * inv * bf2f((unsigned short)g8[2 * j]),
                                  ov[2 * j + 1] * inv * bf2f((unsigned short)g8[2 * j + 1]));
            *(short8*)&Xs[(size_t)row * 64 + (lane & 7) * 8] = pk.s;
        }
        __syncthreads();

        #pragma unroll
        for (int ks = 0; ks < 64; ks += 32) {
            const int cb = ks >> 3;
            short8 a = *(const short8*)&Xs[(wid * 16 + ln) * 64 +
                                           (((quad ^ cb) ^ lnx) * 8)];
            #pragma unroll
            for (int n = 0; n < 4; n++) {
                short8 b = *(const short8*)&Ws[(n * 16 + ln) * 64 +
                                               (((quad ^ cb) ^ lnx) * 8)];
                acc[n] = __builtin_amdgcn_mfma_f32_16x16x32_bf16(a, b, acc[n], 0, 0, 0);
            }
        }
        __syncthreads();
    }

    #pragma unroll
    for (int n = 0; n < 4; n++) {
        int col = n0 + n * 16 + ln;
        float bov = bo[col];
        #pragma unroll
        for (int r = 0; r < 4; r++) {
            int row = m0 + wid * 16 + quad * 4 + r;
            out[(size_t)row * CC + col] = acc[n][r] + bov;
        }
    }
}

// ---------------------------------------------------------------------------
extern "C" void kernel_launch(void* const* d_in, const int* in_sizes, int n_in,
                              void* d_out, int out_size, void* d_ws, size_t ws_size,
                              hipStream_t stream) {
    const float* qx   = (const float*)d_in[0];
    const float* kx   = (const float*)d_in[1];
    const float* vx   = (const float*)d_in[2];
    const float* bias = (const float*)d_in[3];
    const float* wq   = (const float*)d_in[4];
    const float* wk   = (const float*)d_in[5];
    const float* wv   = (const float*)d_in[6];
    const float* wg   = (const float*)d_in[7];
    const float* bg   = (const float*)d_in[8];
    const float* wo   = (const float*)d_in[9];
    const float* bo   = (const float*)d_in[10];
    float* out = (float*)d_out;

    // Workspace layout (peak ~33.8 MB). Opart (KSPLIT=4: 16.8 MB) overlays the
    // old OGb slot + the prep buffers qxb/kxb/vxb/Wb, all dead post-proj.
    char* ws = (char*)d_ws;
    const size_t MB = (size_t)1 << 20;
    unsigned short* wob   = (unsigned short*)(ws);                 // 0.25 MB
    float*          Lpart = (float*)(ws + MB / 4);                 // 0.5 MB (KSPLIT=4)
    unsigned short* Qb    = (unsigned short*)(ws + 1 * MB);        // 4 MB
    unsigned short* Kb    = (unsigned short*)(ws + 5 * MB);        // 4 MB
    unsigned short* VbT   = (unsigned short*)(ws + 9 * MB);        // 4 MB [512][4096]
    unsigned short* Gb    = (unsigned short*)(ws + 13 * MB);       // 4 MB
    unsigned short* qxb   = (unsigned short*)(ws + 21 * MB);       // 2 MB (dead after proj)
    unsigned short* kxb   = (unsigned short*)(ws + 23 * MB);       // 2 MB (dead after proj)
    unsigned short* vxb   = (unsigned short*)(ws + 25 * MB);       // 2 MB (dead after proj)
    unsigned short* Wb    = (unsigned short*)(ws + 27 * MB);       // 1 MB (dead after proj)
    unsigned short* Opart = (unsigned short*)(ws + 17 * MB);       // 16.8 MB (overlays)

    prep_kernel<<<dim3(NN * CC / (256 * 4), 8), 256, 0, stream>>>(
        qx, kx, vx, wq, wk, wv, wg, wo, qxb, kxb, vxb, Wb, wob);
    proj_kernel<<<dim3(32, 16), 256, 0, stream>>>(
        qxb, kxb, vxb, Wb, bg, Qb, Kb, VbT, Gb);
    attn_kernel<<<dim3(64, 8, KSPLIT), 256, 0, stream>>>(
        Qb, Kb, VbT, bias, Opart, Lpart);
    outproj_kernel<<<dim3(64, 4), 256, 0, stream>>>(
        Opart, Lpart, Gb, wob, bo, out);
}

// Round 5
// 227.307 us; speedup vs baseline: 1.2305x; 1.2305x over previous
//
#include <hip/hip_runtime.h>
#include <stdint.h>

// Problem constants: B=1, N=4096, C=256, H=8, D=64, H*D=512
#define NN 4096
#define CC 256
#define HD 512
#define DD 64
#define KSPLIT 3               // 64 k-tiles split 21/21/22 -> grid 1536 = 6 blocks/CU exactly

typedef __attribute__((ext_vector_type(8))) short short8;
typedef __attribute__((ext_vector_type(4))) float floatx4;

__device__ __forceinline__ unsigned short f2bf(float x) {
    union { float f; unsigned int u; } v; v.f = x;
    unsigned int u = v.u + 0x7fffu + ((v.u >> 16) & 1u);
    return (unsigned short)(u >> 16);
}
__device__ __forceinline__ float bf2f(unsigned short s) {
    union { unsigned int u; float f; } v; v.u = ((unsigned int)s) << 16;
    return v.f;
}

// Pack two f32 -> bf16x2 (lo = first arg), RNE. HW instr on gfx950.
#if defined(__has_builtin) && __has_builtin(__builtin_amdgcn_cvt_pk_bf16_f32)
typedef __attribute__((ext_vector_type(2))) __bf16 bf16x2_t;
__device__ __forceinline__ unsigned int pack2bf(float a, float b) {
    union { bf16x2_t v; unsigned int u; } x;
    x.v = __builtin_amdgcn_cvt_pk_bf16_f32(a, b);
    return x.u;
}
#else
__device__ __forceinline__ unsigned int pack2bf(float a, float b) {
    return ((unsigned int)f2bf(b) << 16) | (unsigned int)f2bf(a);
}
#endif

// Async global->LDS, 16 B per lane; LDS dest = wave-uniform base + lane*16.
#define GLOAD_LDS(gp, lp) __builtin_amdgcn_global_load_lds(                    \
    (__attribute__((address_space(1))) void*)(gp),                             \
    (__attribute__((address_space(3))) void*)(lp), 16, 0, 0)

// ---------------------------------------------------------------------------
// Kernel 0: fp32 -> bf16 prep. z selects region. wq pre-scaled by 0.125.
// ---------------------------------------------------------------------------
__global__ __launch_bounds__(256) void prep_kernel(
    const float* __restrict__ qx, const float* __restrict__ kx,
    const float* __restrict__ vx,
    const float* __restrict__ wq, const float* __restrict__ wk,
    const float* __restrict__ wv, const float* __restrict__ wg,
    const float* __restrict__ wo,
    unsigned short* __restrict__ qxb, unsigned short* __restrict__ kxb,
    unsigned short* __restrict__ vxb, unsigned short* __restrict__ Wb,
    unsigned short* __restrict__ wob)
{
    const int z = blockIdx.y;
    const float* src; unsigned short* dst; int n; float s = 1.0f;
    switch (z) {
        case 0: src = qx; dst = qxb; n = NN * CC; break;
        case 1: src = kx; dst = kxb; n = NN * CC; break;
        case 2: src = vx; dst = vxb; n = NN * CC; break;
        case 3: src = wq; dst = Wb;               n = HD * CC; s = 0.125f; break;
        case 4: src = wk; dst = Wb + 1 * HD * CC; n = HD * CC; break;
        case 5: src = wv; dst = Wb + 2 * HD * CC; n = HD * CC; break;
        case 6: src = wg; dst = Wb + 3 * HD * CC; n = HD * CC; break;
        default: src = wo; dst = wob;             n = CC * HD; break;
    }
    int i = (blockIdx.x * 256 + threadIdx.x) * 4;
    if (i < n) {
        float4 v = *(const float4*)&src[i];
        ushort4 p;
        p.x = f2bf(v.x * s); p.y = f2bf(v.y * s);
        p.z = f2bf(v.z * s); p.w = f2bf(v.w * s);
        *(ushort4*)&dst[i] = p;
    }
}

// ---------------------------------------------------------------------------
// Kernel 1: fused projection GEMM. X[4096][256]bf16 @ Wb[2048][256]^T.
// Tile 128x128, BK=64. Staging via global_load_lds (16B/lane) into UNPADDED
// rows (64 shorts = 128 B) with XOR chunk swizzle: LDS slot j of row r holds
// source 8-short chunk j^(r&7); reads XOR the same way -> conflict-free.
// ---------------------------------------------------------------------------
__global__ __launch_bounds__(256, 4) void proj_kernel(
    const unsigned short* __restrict__ qxb, const unsigned short* __restrict__ kxb,
    const unsigned short* __restrict__ vxb, const unsigned short* __restrict__ Wb,
    const float* __restrict__ bg,
    unsigned short* __restrict__ Qb, unsigned short* __restrict__ Kb,
    unsigned short* __restrict__ VbT, unsigned short* __restrict__ Gb)
{
    const int m0 = blockIdx.x * 128;
    const int nb = blockIdx.y;
    const int n0 = nb * 128;
    const int mode = nb >> 2;
    const unsigned short* X = (mode == 1) ? kxb : (mode == 2) ? vxb : qxb;

    const int tid = threadIdx.x;
    const int wid = tid >> 6;
    const int wr = wid >> 1, wc = wid & 1;
    const int lane = tid & 63;
    const int quad = lane >> 4;
    const int ln = lane & 15;
    const int lnx = ln & 7;

    // Xs: 128x64 @ smem[0], Ws: 128x64 @ smem[8192]; transpose scratch reuses
    // the whole buffer (128x136 = 17408 shorts) after the final barrier.
    __shared__ __align__(16) unsigned short smem[128 * 136];
    unsigned short* Xs = smem;
    unsigned short* Ws = smem + 128 * 64;

    floatx4 acc[4][4] = {};

    for (int k0 = 0; k0 < CC; k0 += 64) {
        #pragma unroll
        for (int t = 0; t < 4; t++) {
            int row = wid * 32 + t * 8 + (lane >> 3);
            int c = (lane & 7) ^ (lane >> 3);
            GLOAD_LDS(&X[(size_t)(m0 + row) * CC + k0 + c * 8],
                      &Xs[(wid * 32 + t * 8) * 64]);
            GLOAD_LDS(&Wb[(size_t)(n0 + row) * CC + k0 + c * 8],
                      &Ws[(wid * 32 + t * 8) * 64]);
        }
        __syncthreads();

        #pragma unroll
        for (int ks = 0; ks < 64; ks += 32) {
            const int cb = ks >> 3;    // 0 or 4
            short8 a[4], b[4];
            #pragma unroll
            for (int i = 0; i < 4; i++)
                a[i] = *(const short8*)&Xs[(wr * 64 + i * 16 + ln) * 64 +
                                           (((quad ^ cb) ^ lnx) * 8)];
            #pragma unroll
            for (int j = 0; j < 4; j++)
                b[j] = *(const short8*)&Ws[(wc * 64 + j * 16 + ln) * 64 +
                                           (((quad ^ cb) ^ lnx) * 8)];
            #pragma unroll
            for (int i = 0; i < 4; i++)
                #pragma unroll
                for (int j = 0; j < 4; j++)
                    acc[i][j] = __builtin_amdgcn_mfma_f32_16x16x32_bf16(a[i], b[j], acc[i][j], 0, 0, 0);
        }
        __syncthreads();
    }

    const int subn = nb & 3;
    if (mode != 2) {
        unsigned short* Out = (mode == 0) ? Qb : (mode == 1) ? Kb : Gb;
        #pragma unroll
        for (int i = 0; i < 4; i++) {
            #pragma unroll
            for (int j = 0; j < 4; j++) {
                int col = subn * 128 + wc * 64 + j * 16 + ln;
                float bgv = (mode == 3) ? bg[col] : 0.0f;
                #pragma unroll
                for (int r = 0; r < 4; r++) {
                    int row = m0 + wr * 64 + i * 16 + quad * 4 + r;
                    float v = acc[i][j][r];
                    if (mode == 3) v = 1.0f / (1.0f + __expf(-(v + bgv)));
                    Out[(size_t)row * HD + col] = f2bf(v);
                }
            }
        }
    } else {
        // V: transpose through smem, store coalesced to VbT[col][row]
        #pragma unroll
        for (int i = 0; i < 4; i++) {
            #pragma unroll
            for (int j = 0; j < 4; j++) {
                int cl = wc * 64 + j * 16 + ln;
                #pragma unroll
                for (int r = 0; r < 4; r++) {
                    int rl = wr * 64 + i * 16 + quad * 4 + r;
                    smem[cl * 136 + rl] = f2bf(acc[i][j][r]);
                }
            }
        }
        __syncthreads();
        #pragma unroll
        for (int it = 0; it < 8; it++) {
            int idx = it * 256 + tid;
            int c = idx >> 4, ch = idx & 15;
            short8 vv = *(const short8*)&smem[c * 136 + ch * 8];
            *(short8*)&VbT[(size_t)(subn * 128 + c) * NN + m0 + ch * 8] = vv;
        }
    }
}

// ---------------------------------------------------------------------------
// Kernel 2: flash attention — r0 body (proven 82.6 µs) with ONE change:
// bias registers are software-pipelined. r0 issued the 16 bias loads right
// before __syncthreads(), whose vmcnt(0) drain exposed their full ~600-cy
// L3 latency every tile. Now bv is consumed into S (reg-only) BEFORE the
// staging barrier, and the next tile's bias loads are issued right AFTER it,
// giving them the whole QK/softmax/PV phase to complete before the
// end-of-tile barrier drains them. Everything else is r0 verbatim:
// LDS 25.6 KB -> 6 blocks/CU; grid 1536 = exactly 6/CU; KSPLIT=3.
// ---------------------------------------------------------------------------
__global__ __launch_bounds__(256, 6) void attn_kernel(
    const unsigned short* __restrict__ Qb, const unsigned short* __restrict__ Kb,
    const unsigned short* __restrict__ VbT,
    const float* __restrict__ bias,
    unsigned short* __restrict__ Opart, float* __restrict__ Lpart)
{
    const int h = blockIdx.y;
    const int q0 = blockIdx.x * 64;
    const int sp = blockIdx.z;
    const int tbeg = (sp * 64) / KSPLIT;
    const int tend = ((sp + 1) * 64) / KSPLIT;
    const int tid = threadIdx.x;
    const int wid = tid >> 6;
    const int lane = tid & 63;
    const int quad = lane >> 4;
    const int ln = lane & 15;
    const int lnx = ln & 7;
    const int sc = (lane & 7) ^ (lane >> 3);

    __shared__ __align__(16) unsigned short Ks[64 * 64];   // 8 KB, swizzled
    __shared__ __align__(16) unsigned short Vs[64 * 64];   // 8 KB, swizzled [d][key]
    __shared__ __align__(16) unsigned short Ps[64 * 72];   // 9 KB, padded

    // Q A-fragments in registers for the whole kernel
    const int qrow = q0 + wid * 16 + ln;
    short8 qa0 = *(const short8*)&Qb[(size_t)qrow * HD + h * DD + quad * 8];
    short8 qa1 = *(const short8*)&Qb[(size_t)qrow * HD + h * DD + 32 + quad * 8];

    floatx4 O[4] = {};
    float lsum[4] = {0.0f, 0.0f, 0.0f, 0.0f};

    // bias addressing: lane (ln,quad), wave wid, reg r, block n ->
    // bias[q0 + wid*16 + quad*4 + r][k0 + n*16 + ln]
    const float* bbase = &bias[(size_t)(q0 + wid * 16 + quad * 4) * NN + ln];

    // prologue: bias for the first tile
    float bv[4][4];
    #pragma unroll
    for (int r = 0; r < 4; r++)
        #pragma unroll
        for (int n = 0; n < 4; n++)
            bv[r][n] = bbase[(size_t)r * NN + tbeg * 64 + n * 16];

    for (int kt = tbeg; kt < tend; kt++) {
        const int k0 = kt * 64;
        // async staging: 16 B/lane, LDS slot j of row r <- source chunk j^(r&7)
        #pragma unroll
        for (int t = 0; t < 2; t++) {
            int row = wid * 16 + t * 8 + (lane >> 3);
            GLOAD_LDS(&Kb[(size_t)(k0 + row) * HD + h * DD + sc * 8],
                      &Ks[(wid * 16 + t * 8) * 64]);
            GLOAD_LDS(&VbT[(size_t)(h * DD + row) * NN + k0 + sc * 8],
                      &Vs[(wid * 16 + t * 8) * 64]);
        }

        // consume bv into S (registers only) BEFORE the barrier
        floatx4 S[4];
        #pragma unroll
        for (int n = 0; n < 4; n++)
            S[n] = (floatx4){bv[0][n], bv[1][n], bv[2][n], bv[3][n]};
        __syncthreads();

        // prefetch next tile's bias AFTER the drain -> whole tile to complete
        const int kp = (kt + 1 < tend) ? kt + 1 : kt;   // tail guard (no OOB)
        #pragma unroll
        for (int r = 0; r < 4; r++)
            #pragma unroll
            for (int n = 0; n < 4; n++)
                bv[r][n] = bbase[(size_t)r * NN + kp * 64 + n * 16];

        // S = Q K^T + bias (bias as accumulator init; C layout matches bv[r][n])
        __builtin_amdgcn_s_setprio(1);
        #pragma unroll
        for (int n = 0; n < 4; n++) {
            short8 b0 = *(const short8*)&Ks[(n * 16 + ln) * 64 + ((quad ^ lnx) * 8)];
            S[n] = __builtin_amdgcn_mfma_f32_16x16x32_bf16(qa0, b0, S[n], 0, 0, 0);
            short8 b1 = *(const short8*)&Ks[(n * 16 + ln) * 64 + (((quad ^ 4) ^ lnx) * 8)];
            S[n] = __builtin_amdgcn_mfma_f32_16x16x32_bf16(qa1, b1, S[n], 0, 0, 0);
        }
        __builtin_amdgcn_s_setprio(0);

        // p = exp(S); fixed-max softmax (logits bounded), packed bf16 writes
        #pragma unroll
        for (int r = 0; r < 4; r++) {
            int prow = (wid * 16 + quad * 4 + r) * 72;
            #pragma unroll
            for (int n = 0; n < 4; n += 2) {
                float p0 = __expf(S[n][r]);
                float p1 = __expf(S[n + 1][r]);
                lsum[r] += p0 + p1;
                unsigned int pk = pack2bf(p0, p1);
                Ps[prow + n * 16 + ln] = (unsigned short)(pk & 0xffffu);
                Ps[prow + (n + 1) * 16 + ln] = (unsigned short)(pk >> 16);
            }
        }
        // No barrier: Ps rows are wave-private.

        // O += P V
        __builtin_amdgcn_s_setprio(1);
        #pragma unroll
        for (int ks = 0; ks < 64; ks += 32) {
            const int cb = ks >> 3;
            short8 a = *(const short8*)&Ps[(wid * 16 + ln) * 72 + ks + quad * 8];
            #pragma unroll
            for (int nd = 0; nd < 4; nd++) {
                short8 b = *(const short8*)&Vs[(nd * 16 + ln) * 64 +
                                               (((quad ^ cb) ^ lnx) * 8)];
                O[nd] = __builtin_amdgcn_mfma_f32_16x16x32_bf16(a, b, O[nd], 0, 0, 0);
            }
        }
        __builtin_amdgcn_s_setprio(0);
        __syncthreads();
    }

    // epilogue: one 16-lane reduction for l; store O partial (bf16) + l
    #pragma unroll
    for (int r = 0; r < 4; r++) {
        #pragma unroll
        for (int off = 1; off < 16; off <<= 1)
            lsum[r] += __shfl_xor(lsum[r], off);
        int grow = q0 + wid * 16 + quad * 4 + r;
        size_t base = ((size_t)(sp * 8 + h) * NN + grow) * 64;
        #pragma unroll
        for (int nd = 0; nd < 4; nd++)
            Opart[base + nd * 16 + ln] = f2bf(O[nd][r]);
        if (ln == 0)
            Lpart[(size_t)(sp * 8 + h) * NN + grow] = lsum[r];
    }
}

// ---------------------------------------------------------------------------
// Kernel 2b: combine split-K partials, normalize, gate -> OG bf16 [4096][512]
// ---------------------------------------------------------------------------
__global__ __launch_bounds__(256) void combine_kernel(
    const unsigned short* __restrict__ Opart, const float* __restrict__ Lpart,
    const unsigned short* __restrict__ Gb, unsigned short* __restrict__ OGb)
{
    const int tid = threadIdx.x;
    const int d = tid & 63;
    const int flat = blockIdx.x * 4 + (tid >> 6);   // [0, 8*4096)
    const int h = flat >> 12;
    const int q = flat & (NN - 1);

    float l = 0.0f, o = 0.0f;
    #pragma unroll
    for (int sp = 0; sp < KSPLIT; sp++) {
        size_t idx = (size_t)(sp * 8 + h) * NN + q;
        l += Lpart[idx];
        o += bf2f(Opart[idx * 64 + d]);
    }
    float inv = 1.0f / l;
    int col = h * DD + d;
    float g = bf2f(Gb[(size_t)q * HD + col]);
    OGb[(size_t)q * HD + col] = f2bf(o * inv * g);
}

// ---------------------------------------------------------------------------
// Kernel 3: out = OG[4096][512]bf16 @ wob^T([256][512]bf16) + bo -> fp32
// ---------------------------------------------------------------------------
__global__ __launch_bounds__(256, 4) void outproj_kernel(
    const unsigned short* __restrict__ OGb, const unsigned short* __restrict__ wob,
    const float* __restrict__ bo, float* __restrict__ out)
{
    const int m0 = blockIdx.x * 64;
    const int n0 = blockIdx.y * 64;
    const int tid = threadIdx.x;
    const int wid = tid >> 6;
    const int lane = tid & 63;
    const int quad = lane >> 4;
    const int ln = lane & 15;
    const int lnx = ln & 7;

    __shared__ __align__(16) unsigned short Xs[64 * 64];
    __shared__ __align__(16) unsigned short Ws[64 * 64];

    floatx4 acc[4] = {};

    for (int k0 = 0; k0 < HD; k0 += 64) {
        #pragma unroll
        for (int t = 0; t < 2; t++) {
            int row = wid * 16 + t * 8 + (lane >> 3);
            int c = (lane & 7) ^ (lane >> 3);
            GLOAD_LDS(&OGb[(size_t)(m0 + row) * HD + k0 + c * 8],
                      &Xs[(wid * 16 + t * 8) * 64]);
            GLOAD_LDS(&wob[(size_t)(n0 + row) * HD + k0 + c * 8],
                      &Ws[(wid * 16 + t * 8) * 64]);
        }
        __syncthreads();

        #pragma unroll
        for (int ks = 0; ks < 64; ks += 32) {
            const int cb = ks >> 3;
            short8 a = *(const short8*)&Xs[(wid * 16 + ln) * 64 +
                                           (((quad ^ cb) ^ lnx) * 8)];
            #pragma unroll
            for (int n = 0; n < 4; n++) {
                short8 b = *(const short8*)&Ws[(n * 16 + ln) * 64 +
                                               (((quad ^ cb) ^ lnx) * 8)];
                acc[n] = __builtin_amdgcn_mfma_f32_16x16x32_bf16(a, b, acc[n], 0, 0, 0);
            }
        }
        __syncthreads();
    }

    #pragma unroll
    for (int n = 0; n < 4; n++) {
        int col = n0 + n * 16 + ln;
        float bov = bo[col];
        #pragma unroll
        for (int r = 0; r < 4; r++) {
            int row = m0 + wid * 16 + quad * 4 + r;
            out[(size_t)row * CC + col] = acc[n][r] + bov;
        }
    }
}

// ---------------------------------------------------------------------------
extern "C" void kernel_launch(void* const* d_in, const int* in_sizes, int n_in,
                              void* d_out, int out_size, void* d_ws, size_t ws_size,
                              hipStream_t stream) {
    const float* qx   = (const float*)d_in[0];
    const float* kx   = (const float*)d_in[1];
    const float* vx   = (const float*)d_in[2];
    const float* bias = (const float*)d_in[3];
    const float* wq   = (const float*)d_in[4];
    const float* wk   = (const float*)d_in[5];
    const float* wv   = (const float*)d_in[6];
    const float* wg   = (const float*)d_in[7];
    const float* bg   = (const float*)d_in[8];
    const float* wo   = (const float*)d_in[9];
    const float* bo   = (const float*)d_in[10];
    float* out = (float*)d_out;

    // Workspace layout (peak ~34 MB). Opart overlays the prep buffers
    // qxb/kxb/vxb/Wb, which are dead once proj_kernel completes.
    char* ws = (char*)d_ws;
    const size_t MB = (size_t)1 << 20;
    unsigned short* wob   = (unsigned short*)(ws);                 // 0.25 MB
    float*          Lpart = (float*)(ws + MB / 4);                 // 0.4 MB
    unsigned short* Qb    = (unsigned short*)(ws + 1 * MB);        // 4 MB
    unsigned short* Kb    = (unsigned short*)(ws + 5 * MB);        // 4 MB
    unsigned short* VbT   = (unsigned short*)(ws + 9 * MB);        // 4 MB [512][4096]
    unsigned short* Gb    = (unsigned short*)(ws + 13 * MB);       // 4 MB
    unsigned short* OGb   = (unsigned short*)(ws + 17 * MB);       // 4 MB
    unsigned short* qxb   = (unsigned short*)(ws + 21 * MB);       // 2 MB (dead after proj)
    unsigned short* kxb   = (unsigned short*)(ws + 23 * MB);       // 2 MB (dead after proj)
    unsigned short* vxb   = (unsigned short*)(ws + 25 * MB);       // 2 MB (dead after proj)
    unsigned short* Wb    = (unsigned short*)(ws + 27 * MB);       // 1 MB (dead after proj)
    unsigned short* Opart = (unsigned short*)(ws + 21 * MB);       // 12.6 MB (overlays)

    prep_kernel<<<dim3(NN * CC / (256 * 4), 8), 256, 0, stream>>>(
        qx, kx, vx, wq, wk, wv, wg, wo, qxb, kxb, vxb, Wb, wob);
    proj_kernel<<<dim3(32, 16), 256, 0, stream>>>(
        qxb, kxb, vxb, Wb, bg, Qb, Kb, VbT, Gb);
    attn_kernel<<<dim3(64, 8, KSPLIT), 256, 0, stream>>>(
        Qb, Kb, VbT, bias, Opart, Lpart);
    combine_kernel<<<dim3(NN * 8 / 4), 256, 0, stream>>>(
        Opart, Lpart, Gb, OGb);
    outproj_kernel<<<dim3(64, 4), 256, 0, stream>>>(
        OGb, wob, bo, out);
}

// Round 6
// 209.241 us; speedup vs baseline: 1.3368x; 1.0863x over previous
//
#include <hip/hip_runtime.h>
#include <stdint.h>

// Problem constants: B=1, N=4096, C=256, H=8, D=64, H*D=512
#define NN 4096
#define CC 256
#define HD 512
#define DD 64
#define KSPLIT 3               // 64 k-tiles split 21/21/22 -> grid 1536 = 6 blocks/CU exactly

typedef __attribute__((ext_vector_type(8))) short short8;
typedef __attribute__((ext_vector_type(4))) float floatx4;

__device__ __forceinline__ unsigned short f2bf(float x) {
    union { float f; unsigned int u; } v; v.f = x;
    unsigned int u = v.u + 0x7fffu + ((v.u >> 16) & 1u);
    return (unsigned short)(u >> 16);
}
__device__ __forceinline__ float bf2f(unsigned short s) {
    union { unsigned int u; float f; } v; v.u = ((unsigned int)s) << 16;
    return v.f;
}

// Pack two f32 -> bf16x2 (lo = first arg), RNE. HW instr on gfx950.
#if defined(__has_builtin) && __has_builtin(__builtin_amdgcn_cvt_pk_bf16_f32)
typedef __attribute__((ext_vector_type(2))) __bf16 bf16x2_t;
__device__ __forceinline__ unsigned int pack2bf(float a, float b) {
    union { bf16x2_t v; unsigned int u; } x;
    x.v = __builtin_amdgcn_cvt_pk_bf16_f32(a, b);
    return x.u;
}
#else
__device__ __forceinline__ unsigned int pack2bf(float a, float b) {
    return ((unsigned int)f2bf(b) << 16) | (unsigned int)f2bf(a);
}
#endif

// Async global->LDS, 16 B per lane; LDS dest = wave-uniform base + lane*16.
#define GLOAD_LDS(gp, lp) __builtin_amdgcn_global_load_lds(                    \
    (__attribute__((address_space(1))) void*)(gp),                             \
    (__attribute__((address_space(3))) void*)(lp), 16, 0, 0)

// ---------------------------------------------------------------------------
// Kernel 0: fp32 -> bf16 prep. z selects region. wq pre-scaled by 0.125.
// ---------------------------------------------------------------------------
__global__ __launch_bounds__(256) void prep_kernel(
    const float* __restrict__ qx, const float* __restrict__ kx,
    const float* __restrict__ vx,
    const float* __restrict__ wq, const float* __restrict__ wk,
    const float* __restrict__ wv, const float* __restrict__ wg,
    const float* __restrict__ wo,
    unsigned short* __restrict__ qxb, unsigned short* __restrict__ kxb,
    unsigned short* __restrict__ vxb, unsigned short* __restrict__ Wb,
    unsigned short* __restrict__ wob)
{
    const int z = blockIdx.y;
    const float* src; unsigned short* dst; int n; float s = 1.0f;
    switch (z) {
        case 0: src = qx; dst = qxb; n = NN * CC; break;
        case 1: src = kx; dst = kxb; n = NN * CC; break;
        case 2: src = vx; dst = vxb; n = NN * CC; break;
        case 3: src = wq; dst = Wb;               n = HD * CC; s = 0.125f; break;
        case 4: src = wk; dst = Wb + 1 * HD * CC; n = HD * CC; break;
        case 5: src = wv; dst = Wb + 2 * HD * CC; n = HD * CC; break;
        case 6: src = wg; dst = Wb + 3 * HD * CC; n = HD * CC; break;
        default: src = wo; dst = wob;             n = CC * HD; break;
    }
    int i = (blockIdx.x * 256 + threadIdx.x) * 4;
    if (i < n) {
        float4 v = *(const float4*)&src[i];
        ushort4 p;
        p.x = f2bf(v.x * s); p.y = f2bf(v.y * s);
        p.z = f2bf(v.z * s); p.w = f2bf(v.w * s);
        *(ushort4*)&dst[i] = p;
    }
}

// ---------------------------------------------------------------------------
// Kernel 1: fused projection GEMM. X[4096][256]bf16 @ Wb[2048][256]^T.
// Tile 128x128, BK=64, now DOUBLE-BUFFERED staging: grid 512 = 2 blocks/CU,
// so there is little TLP to hide the per-K-step vmcnt(0) barrier drain —
// prefetching K-step t+1 before computing t hides 3 of the 4 drains.
// LDS 64 KB (2 x {Xs,Ws}) -> cap 2 blocks/CU = actual residency (no loss).
// Same XOR chunk swizzle as before; transpose scratch reuses buffer 0+1.
// ---------------------------------------------------------------------------
__global__ __launch_bounds__(256, 2) void proj_kernel(
    const unsigned short* __restrict__ qxb, const unsigned short* __restrict__ kxb,
    const unsigned short* __restrict__ vxb, const unsigned short* __restrict__ Wb,
    const float* __restrict__ bg,
    unsigned short* __restrict__ Qb, unsigned short* __restrict__ Kb,
    unsigned short* __restrict__ VbT, unsigned short* __restrict__ Gb)
{
    const int m0 = blockIdx.x * 128;
    const int nb = blockIdx.y;
    const int n0 = nb * 128;
    const int mode = nb >> 2;
    const unsigned short* X = (mode == 1) ? kxb : (mode == 2) ? vxb : qxb;

    const int tid = threadIdx.x;
    const int wid = tid >> 6;
    const int wr = wid >> 1, wc = wid & 1;
    const int lane = tid & 63;
    const int quad = lane >> 4;
    const int ln = lane & 15;
    const int lnx = ln & 7;

    // buf bf: Xs @ smem + bf*16384, Ws @ smem + bf*16384 + 8192 (shorts).
    // Transpose scratch (128x136 = 17408 shorts) reuses smem after the loop.
    __shared__ __align__(16) unsigned short smem[4 * 128 * 64];

    floatx4 acc[4][4] = {};

    auto STAGE = [&](int k0, int bf) {
        unsigned short* Xs = smem + bf * 16384;
        unsigned short* Ws = smem + bf * 16384 + 8192;
        #pragma unroll
        for (int t = 0; t < 4; t++) {
            int row = wid * 32 + t * 8 + (lane >> 3);
            int c = (lane & 7) ^ (lane >> 3);
            GLOAD_LDS(&X[(size_t)(m0 + row) * CC + k0 + c * 8],
                      &Xs[(wid * 32 + t * 8) * 64]);
            GLOAD_LDS(&Wb[(size_t)(n0 + row) * CC + k0 + c * 8],
                      &Ws[(wid * 32 + t * 8) * 64]);
        }
    };

    STAGE(0, 0);
    __syncthreads();

    for (int it = 0; it < 4; it++) {
        const int bf = it & 1;
        if (it + 1 < 4) STAGE((it + 1) * 64, bf ^ 1);

        const unsigned short* Xs = smem + bf * 16384;
        const unsigned short* Ws = smem + bf * 16384 + 8192;
        #pragma unroll
        for (int ks = 0; ks < 64; ks += 32) {
            const int cb = ks >> 3;    // 0 or 4
            short8 a[4], b[4];
            #pragma unroll
            for (int i = 0; i < 4; i++)
                a[i] = *(const short8*)&Xs[(wr * 64 + i * 16 + ln) * 64 +
                                           (((quad ^ cb) ^ lnx) * 8)];
            #pragma unroll
            for (int j = 0; j < 4; j++)
                b[j] = *(const short8*)&Ws[(wc * 64 + j * 16 + ln) * 64 +
                                           (((quad ^ cb) ^ lnx) * 8)];
            #pragma unroll
            for (int i = 0; i < 4; i++)
                #pragma unroll
                for (int j = 0; j < 4; j++)
                    acc[i][j] = __builtin_amdgcn_mfma_f32_16x16x32_bf16(a[i], b[j], acc[i][j], 0, 0, 0);
        }
        __syncthreads();   // drains prefetch; also protects buf reuse at it+2
    }

    const int subn = nb & 3;
    if (mode != 2) {
        unsigned short* Out = (mode == 0) ? Qb : (mode == 1) ? Kb : Gb;
        #pragma unroll
        for (int i = 0; i < 4; i++) {
            #pragma unroll
            for (int j = 0; j < 4; j++) {
                int col = subn * 128 + wc * 64 + j * 16 + ln;
                float bgv = (mode == 3) ? bg[col] : 0.0f;
                #pragma unroll
                for (int r = 0; r < 4; r++) {
                    int row = m0 + wr * 64 + i * 16 + quad * 4 + r;
                    float v = acc[i][j][r];
                    if (mode == 3) v = 1.0f / (1.0f + __expf(-(v + bgv)));
                    Out[(size_t)row * HD + col] = f2bf(v);
                }
            }
        }
    } else {
        // V: transpose through smem, store coalesced to VbT[col][row]
        #pragma unroll
        for (int i = 0; i < 4; i++) {
            #pragma unroll
            for (int j = 0; j < 4; j++) {
                int cl = wc * 64 + j * 16 + ln;
                #pragma unroll
                for (int r = 0; r < 4; r++) {
                    int rl = wr * 64 + i * 16 + quad * 4 + r;
                    smem[cl * 136 + rl] = f2bf(acc[i][j][r]);
                }
            }
        }
        __syncthreads();
        #pragma unroll
        for (int it = 0; it < 8; it++) {
            int idx = it * 256 + tid;
            int c = idx >> 4, ch = idx & 15;
            short8 vv = *(const short8*)&smem[c * 136 + ch * 8];
            *(short8*)&VbT[(size_t)(subn * 128 + c) * NN + m0 + ch * 8] = vv;
        }
    }
}

// ---------------------------------------------------------------------------
// Kernel 2: flash attention, split-K=3 (tiles 21/21/22), Tk=64, Q in regs.
// r0 body VERBATIM (proven 82.6 µs / FETCH 76 MB): any perturbation of this
// schedule (occupancy, layout, bias timing) measurably broke the L3 phase
// equilibrium across heads in rounds 1-5. Do not touch.
// LDS 25.6 KB -> 6 blocks/CU; grid 1536 = exactly 6/CU (no tail).
// ---------------------------------------------------------------------------
__global__ __launch_bounds__(256, 6) void attn_kernel(
    const unsigned short* __restrict__ Qb, const unsigned short* __restrict__ Kb,
    const unsigned short* __restrict__ VbT,
    const float* __restrict__ bias,
    unsigned short* __restrict__ Opart, float* __restrict__ Lpart)
{
    const int h = blockIdx.y;
    const int q0 = blockIdx.x * 64;
    const int sp = blockIdx.z;
    const int tbeg = (sp * 64) / KSPLIT;
    const int tend = ((sp + 1) * 64) / KSPLIT;
    const int tid = threadIdx.x;
    const int wid = tid >> 6;
    const int lane = tid & 63;
    const int quad = lane >> 4;
    const int ln = lane & 15;
    const int lnx = ln & 7;
    const int sc = (lane & 7) ^ (lane >> 3);

    __shared__ __align__(16) unsigned short Ks[64 * 64];   // 8 KB, swizzled
    __shared__ __align__(16) unsigned short Vs[64 * 64];   // 8 KB, swizzled [d][key]
    __shared__ __align__(16) unsigned short Ps[64 * 72];   // 9 KB, padded

    // Q A-fragments in registers for the whole kernel
    const int qrow = q0 + wid * 16 + ln;
    short8 qa0 = *(const short8*)&Qb[(size_t)qrow * HD + h * DD + quad * 8];
    short8 qa1 = *(const short8*)&Qb[(size_t)qrow * HD + h * DD + 32 + quad * 8];

    floatx4 O[4] = {};
    float lsum[4] = {0.0f, 0.0f, 0.0f, 0.0f};

    for (int kt = tbeg; kt < tend; kt++) {
        const int k0 = kt * 64;
        // async staging: 16 B/lane, LDS slot j of row r <- source chunk j^(r&7)
        #pragma unroll
        for (int t = 0; t < 2; t++) {
            int row = wid * 16 + t * 8 + (lane >> 3);
            int c = (lane & 7) ^ (lane >> 3);
            GLOAD_LDS(&Kb[(size_t)(k0 + row) * HD + h * DD + c * 8],
                      &Ks[(wid * 16 + t * 8) * 64]);
            GLOAD_LDS(&VbT[(size_t)(h * DD + row) * NN + k0 + c * 8],
                      &Vs[(wid * 16 + t * 8) * 64]);
        }

        // bias -> registers (overlaps barrier drain); feeds MFMA C-init
        float bv[4][4];
        #pragma unroll
        for (int r = 0; r < 4; r++) {
            const float* brow = &bias[(size_t)(q0 + wid * 16 + quad * 4 + r) * NN + k0];
            #pragma unroll
            for (int n = 0; n < 4; n++) bv[r][n] = brow[n * 16 + ln];
        }
        __syncthreads();

        // S = Q K^T + bias (bias as accumulator init; C layout matches bv[r][n])
        floatx4 S[4];
        #pragma unroll
        for (int n = 0; n < 4; n++)
            S[n] = (floatx4){bv[0][n], bv[1][n], bv[2][n], bv[3][n]};
        #pragma unroll
        for (int n = 0; n < 4; n++) {
            short8 b0 = *(const short8*)&Ks[(n * 16 + ln) * 64 + ((quad ^ lnx) * 8)];
            S[n] = __builtin_amdgcn_mfma_f32_16x16x32_bf16(qa0, b0, S[n], 0, 0, 0);
            short8 b1 = *(const short8*)&Ks[(n * 16 + ln) * 64 + (((quad ^ 4) ^ lnx) * 8)];
            S[n] = __builtin_amdgcn_mfma_f32_16x16x32_bf16(qa1, b1, S[n], 0, 0, 0);
        }

        // p = exp(S); fixed-max softmax (logits bounded), packed bf16 writes
        #pragma unroll
        for (int r = 0; r < 4; r++) {
            int prow = (wid * 16 + quad * 4 + r) * 72;
            #pragma unroll
            for (int n = 0; n < 4; n += 2) {
                float p0 = __expf(S[n][r]);
                float p1 = __expf(S[n + 1][r]);
                lsum[r] += p0 + p1;
                unsigned int pk = pack2bf(p0, p1);
                Ps[prow + n * 16 + ln] = (unsigned short)(pk & 0xffffu);
                Ps[prow + (n + 1) * 16 + ln] = (unsigned short)(pk >> 16);
            }
        }
        // No barrier: Ps rows are wave-private.

        // O += P V
        #pragma unroll
        for (int ks = 0; ks < 64; ks += 32) {
            const int cb = ks >> 3;
            short8 a = *(const short8*)&Ps[(wid * 16 + ln) * 72 + ks + quad * 8];
            #pragma unroll
            for (int nd = 0; nd < 4; nd++) {
                short8 b = *(const short8*)&Vs[(nd * 16 + ln) * 64 +
                                               (((quad ^ cb) ^ lnx) * 8)];
                O[nd] = __builtin_amdgcn_mfma_f32_16x16x32_bf16(a, b, O[nd], 0, 0, 0);
            }
        }
        __syncthreads();
    }

    // epilogue: one 16-lane reduction for l; store O partial (bf16) + l
    #pragma unroll
    for (int r = 0; r < 4; r++) {
        #pragma unroll
        for (int off = 1; off < 16; off <<= 1)
            lsum[r] += __shfl_xor(lsum[r], off);
        int grow = q0 + wid * 16 + quad * 4 + r;
        size_t base = ((size_t)(sp * 8 + h) * NN + grow) * 64;
        #pragma unroll
        for (int nd = 0; nd < 4; nd++)
            Opart[base + nd * 16 + ln] = f2bf(O[nd][r]);
        if (ln == 0)
            Lpart[(size_t)(sp * 8 + h) * NN + grow] = lsum[r];
    }
}

// ---------------------------------------------------------------------------
// Kernel 2b: combine split-K partials, normalize, gate -> OG bf16 [4096][512]
// ---------------------------------------------------------------------------
__global__ __launch_bounds__(256) void combine_kernel(
    const unsigned short* __restrict__ Opart, const float* __restrict__ Lpart,
    const unsigned short* __restrict__ Gb, unsigned short* __restrict__ OGb)
{
    const int tid = threadIdx.x;
    const int d = tid & 63;
    const int flat = blockIdx.x * 4 + (tid >> 6);   // [0, 8*4096)
    const int h = flat >> 12;
    const int q = flat & (NN - 1);

    float l = 0.0f, o = 0.0f;
    #pragma unroll
    for (int sp = 0; sp < KSPLIT; sp++) {
        size_t idx = (size_t)(sp * 8 + h) * NN + q;
        l += Lpart[idx];
        o += bf2f(Opart[idx * 64 + d]);
    }
    float inv = 1.0f / l;
    int col = h * DD + d;
    float g = bf2f(Gb[(size_t)q * HD + col]);
    OGb[(size_t)q * HD + col] = f2bf(o * inv * g);
}

// ---------------------------------------------------------------------------
// Kernel 3: out = OG[4096][512]bf16 @ wob^T([256][512]bf16) + bo -> fp32.
// Grid 256 = 1 block/CU: zero TLP to hide the 8 per-K-step barrier drains,
// so staging is now DOUBLE-BUFFERED (prefetch k+1 before computing k) —
// hides 7 of 8 drains. LDS 32 KB, residency unchanged (grid-limited).
// ---------------------------------------------------------------------------
__global__ __launch_bounds__(256, 2) void outproj_kernel(
    const unsigned short* __restrict__ OGb, const unsigned short* __restrict__ wob,
    const float* __restrict__ bo, float* __restrict__ out)
{
    const int m0 = blockIdx.x * 64;
    const int n0 = blockIdx.y * 64;
    const int tid = threadIdx.x;
    const int wid = tid >> 6;
    const int lane = tid & 63;
    const int quad = lane >> 4;
    const int ln = lane & 15;
    const int lnx = ln & 7;

    __shared__ __align__(16) unsigned short Xs[2][64 * 64];
    __shared__ __align__(16) unsigned short Ws[2][64 * 64];

    floatx4 acc[4] = {};

    auto STAGE = [&](int k0, int bf) {
        #pragma unroll
        for (int t = 0; t < 2; t++) {
            int row = wid * 16 + t * 8 + (lane >> 3);
            int c = (lane & 7) ^ (lane >> 3);
            GLOAD_LDS(&OGb[(size_t)(m0 + row) * HD + k0 + c * 8],
                      &Xs[bf][(wid * 16 + t * 8) * 64]);
            GLOAD_LDS(&wob[(size_t)(n0 + row) * HD + k0 + c * 8],
                      &Ws[bf][(wid * 16 + t * 8) * 64]);
        }
    };

    STAGE(0, 0);
    __syncthreads();

    for (int it = 0; it < 8; it++) {
        const int bf = it & 1;
        if (it + 1 < 8) STAGE((it + 1) * 64, bf ^ 1);

        #pragma unroll
        for (int ks = 0; ks < 64; ks += 32) {
            const int cb = ks >> 3;
            short8 a = *(const short8*)&Xs[bf][(wid * 16 + ln) * 64 +
                                              (((quad ^ cb) ^ lnx) * 8)];
            #pragma unroll
            for (int n = 0; n < 4; n++) {
                short8 b = *(const short8*)&Ws[bf][(n * 16 + ln) * 64 +
                                                   (((quad ^ cb) ^ lnx) * 8)];
                acc[n] = __builtin_amdgcn_mfma_f32_16x16x32_bf16(a, b, acc[n], 0, 0, 0);
            }
        }
        __syncthreads();   // drains prefetch; also protects buf reuse at it+2
    }

    #pragma unroll
    for (int n = 0; n < 4; n++) {
        int col = n0 + n * 16 + ln;
        float bov = bo[col];
        #pragma unroll
        for (int r = 0; r < 4; r++) {
            int row = m0 + wid * 16 + quad * 4 + r;
            out[(size_t)row * CC + col] = acc[n][r] + bov;
        }
    }
}

// ---------------------------------------------------------------------------
extern "C" void kernel_launch(void* const* d_in, const int* in_sizes, int n_in,
                              void* d_out, int out_size, void* d_ws, size_t ws_size,
                              hipStream_t stream) {
    const float* qx   = (const float*)d_in[0];
    const float* kx   = (const float*)d_in[1];
    const float* vx   = (const float*)d_in[2];
    const float* bias = (const float*)d_in[3];
    const float* wq   = (const float*)d_in[4];
    const float* wk   = (const float*)d_in[5];
    const float* wv   = (const float*)d_in[6];
    const float* wg   = (const float*)d_in[7];
    const float* bg   = (const float*)d_in[8];
    const float* wo   = (const float*)d_in[9];
    const float* bo   = (const float*)d_in[10];
    float* out = (float*)d_out;

    // Workspace layout (peak ~34 MB). Opart overlays the prep buffers
    // qxb/kxb/vxb/Wb, which are dead once proj_kernel completes.
    char* ws = (char*)d_ws;
    const size_t MB = (size_t)1 << 20;
    unsigned short* wob   = (unsigned short*)(ws);                 // 0.25 MB
    float*          Lpart = (float*)(ws + MB / 4);                 // 0.4 MB
    unsigned short* Qb    = (unsigned short*)(ws + 1 * MB);        // 4 MB
    unsigned short* Kb    = (unsigned short*)(ws + 5 * MB);        // 4 MB
    unsigned short* VbT   = (unsigned short*)(ws + 9 * MB);        // 4 MB [512][4096]
    unsigned short* Gb    = (unsigned short*)(ws + 13 * MB);       // 4 MB
    unsigned short* OGb   = (unsigned short*)(ws + 17 * MB);       // 4 MB
    unsigned short* qxb   = (unsigned short*)(ws + 21 * MB);       // 2 MB (dead after proj)
    unsigned short* kxb   = (unsigned short*)(ws + 23 * MB);       // 2 MB (dead after proj)
    unsigned short* vxb   = (unsigned short*)(ws + 25 * MB);       // 2 MB (dead after proj)
    unsigned short* Wb    = (unsigned short*)(ws + 27 * MB);       // 1 MB (dead after proj)
    unsigned short* Opart = (unsigned short*)(ws + 21 * MB);       // 12.6 MB (overlays)

    prep_kernel<<<dim3(NN * CC / (256 * 4), 8), 256, 0, stream>>>(
        qx, kx, vx, wq, wk, wv, wg, wo, qxb, kxb, vxb, Wb, wob);
    proj_kernel<<<dim3(32, 16), 256, 0, stream>>>(
        qxb, kxb, vxb, Wb, bg, Qb, Kb, VbT, Gb);
    attn_kernel<<<dim3(64, 8, KSPLIT), 256, 0, stream>>>(
        Qb, Kb, VbT, bias, Opart, Lpart);
    combine_kernel<<<dim3(NN * 8 / 4), 256, 0, stream>>>(
        Opart, Lpart, Gb, OGb);
    outproj_kernel<<<dim3(64, 4), 256, 0, stream>>>(
        OGb, wob, bo, out);
}